// Round 3
// baseline (2620.096 us; speedup 1.0000x reference)
//
#include <hip/hip_runtime.h>
#include <math.h>

#define NROWS 131072
#define DIMD  128
#define KCB   1024
#define NLEV  4

#define RB  128            // rows per block
#define KT  128            // k per tile
#define NT  (KCB / KT)     // 8 tiles

// LDS: rS[128][132] + eS[128][132] + C_S[1024] + A_S[128] + commitAcc[128]
//      + usageAcc[128] + codesS[128*4](int) = 143360 bytes
#define LDS_BYTES 143360

// expm1 via degree-7 Taylor; |s| <= ~0.3, trunc err < 5e-9. Analytic softmax
// stats (noise-free vs ref's f32 softmax; zero-mean diff averages out over N).
__device__ __forceinline__ float expm1_poly(float s) {
    float p = fmaf(s, 1.0f / 5040.0f, 1.0f / 720.0f);
    p = fmaf(s, p, 1.0f / 120.0f);
    p = fmaf(s, p, 1.0f / 24.0f);
    p = fmaf(s, p, 1.0f / 6.0f);
    p = fmaf(s, p, 0.5f);
    p = fmaf(s, p, 1.0f);
    return s * p;
}

// numpy pairwise sum of squares for n=128 contiguous f32, replicating the
// AVX512-dispatched path: 8 vector accumulators (vstep=16, n=8*16 exactly,
// zero loop iterations), lanewise combine ((c0+c1)+(c2+c3))+((c4+c5)+(c6+c7)),
// then GCC _mm512_reduce_add_ps halving tree. Do NOT reassociate (IEEE-strict).
__device__ __forceinline__ float np_sumsq128(const float* __restrict__ p) {
    float q[16];
    #pragma unroll
    for (int lane = 0; lane < 16; ++lane) {
        float c[8];
        #pragma unroll
        for (int j = 0; j < 8; ++j) { float v = p[16 * j + lane]; c[j] = v * v; }
        float s01 = c[0] + c[1], s23 = c[2] + c[3];
        float s45 = c[4] + c[5], s67 = c[6] + c[7];
        q[lane] = (s01 + s23) + (s45 + s67);
    }
    float t[8];
    #pragma unroll
    for (int j = 0; j < 8; ++j) t[j] = q[j] + q[j + 8];
    float u[4];
    #pragma unroll
    for (int j = 0; j < 4; ++j) u[j] = t[j] + t[j + 4];
    float w0 = u[0] + u[2], w1 = u[1] + u[3];
    return w0 + w1;
}

__global__ __launch_bounds__(256, 1)
void rvq_main(const float* __restrict__ x, const float* __restrict__ cb,
              float* __restrict__ out, const float* __restrict__ e2g,
              double* __restrict__ lossAcc)
{
    extern __shared__ float smem[];
    float* rS        = smem;                    // RB*132 (f32 residual chain)
    float* eS        = rS + RB * 132;           // KT*132
    float* C_S       = eS + KT * 132;           // KCB  (np-tree sum(e^2))
    float* A_S       = C_S + KCB;               // RB   (np-tree sum(r^2))
    float* commitAcc = A_S + RB;                // RB
    float* usageAcc  = commitAcc + RB;          // RB
    int*   codesS    = (int*)(usageAcc + RB);   // RB*NLEV

    const int tid = threadIdx.x;
    const int tx  = tid & 15;        // lane within 16-thread row-group
    const int ty  = tid >> 4;        // 16 groups * 8 rows = 128 rows
    const int rowBase = blockIdx.x * RB;

    float4* rS4 = (float4*)rS;
    float4* eS4 = (float4*)eS;
    const float4* x4 = (const float4*)x;
    float4* out4 = (float4*)out;

    // ---- init: residual = x (f32 chain start) ----
    #pragma unroll
    for (int i = 0; i < 8; ++i) {
        int row = 8 * ty + i;
        size_t n = (size_t)rowBase + row;
        rS4[row * 33 + 2 * tx]     = x4[n * 32 + 2 * tx];
        rS4[row * 33 + 2 * tx + 1] = x4[n * 32 + 2 * tx + 1];
    }
    if (tid < RB) { usageAcc[tid] = 0.0f; commitAcc[tid] = 0.0f; }

    for (int l = 0; l < NLEV; ++l) {
        __syncthreads();   // rS chain from previous level visible
        #pragma unroll
        for (int j = 0; j < KCB / 256; ++j)
            C_S[tid + j * 256] = e2g[l * KCB + tid + j * 256];
        if (tid < RB)
            A_S[tid] = np_sumsq128(rS + tid * 132);   // np pairwise tree

        float dmin[8], dev[8], sw[8];
        int   kmin[8];
        #pragma unroll
        for (int i = 0; i < 8; ++i) {
            dmin[i] = __builtin_inff(); kmin[i] = 0;
            dev[i] = 0.0f; sw[i] = 0.0f;
        }

        const float* cbL = cb + (size_t)l * KCB * DIMD;
        const float4* cbL4 = (const float4*)cbL;

        __syncthreads();   // C_S / A_S ready

        for (int kt = 0; kt < NT; ++kt) {
            // stage raw E tile, d-block xor-swizzled by (kk>>3)&7
            #pragma unroll
            for (int it = 0; it < (KT * 32) / 256; ++it) {
                int f  = it * 256 + tid;
                int kk = f >> 5;
                int d4 = f & 31;
                eS4[kk * 33 + (d4 ^ ((kk >> 3) & 7))] =
                    cbL4[(size_t)(kt * KT + kk) * 32 + d4];
            }
            __syncthreads();

            // B = sequential ascending-d fp32 FMA chain from 0 (BLAS sgemm order)
            float b[8][8];
            #pragma unroll
            for (int i = 0; i < 8; ++i)
                #pragma unroll
                for (int j = 0; j < 8; ++j) b[i][j] = 0.0f;

            const int rb0 = (8 * ty) * 33;
            const int eb0 = (8 * tx) * 33;
            const int sw0 = tx & 7;

            #pragma unroll 2
            for (int db = 0; db < 32; ++db) {
                float4 r4[8], e4[8];
                #pragma unroll
                for (int i = 0; i < 8; ++i) r4[i] = rS4[rb0 + i * 33 + db];
                const int ep = db ^ sw0;
                #pragma unroll
                for (int j = 0; j < 8; ++j) e4[j] = eS4[eb0 + j * 33 + ep];
                #pragma unroll
                for (int i = 0; i < 8; ++i) {
                    #pragma unroll
                    for (int j = 0; j < 8; ++j) {
                        b[i][j] = fmaf(r4[i].x, e4[j].x, b[i][j]);
                        b[i][j] = fmaf(r4[i].y, e4[j].y, b[i][j]);
                        b[i][j] = fmaf(r4[i].z, e4[j].z, b[i][j]);
                        b[i][j] = fmaf(r4[i].w, e4[j].w, b[i][j]);
                    }
                }
            }

            const int kb = kt * KT + 8 * tx;
            #pragma unroll
            for (int i = 0; i < 8; ++i) {
                const float Ar = A_S[8 * ty + i];
                #pragma unroll
                for (int j = 0; j < 8; ++j) {
                    // d32 = fl32(fl32(A - 2B) + C): the reference's fp32 value
                    float m2b = 2.0f * b[i][j];          // exact
                    float t1  = Ar - m2b;                // fl32 @ ulp(128)
                    float d32 = t1 + C_S[kb + j];        // fl32 @ ulp(128)
                    if (d32 < dmin[i]) { dmin[i] = d32; kmin[i] = kb + j; }
                    float su = Ar - d32;                 // Sterbenz: exact
                    float em = expm1_poly(su);
                    dev[i] += em;
                    sw[i]  += su;
                    sw[i]   = fmaf(su, em, sw[i]);
                }
            }
            __syncthreads();   // protect eS for next tile
        }

        // merge across the 16 lanes: min with FIRST-INDEX tie-break (np.argmin)
        #pragma unroll
        for (int i = 0; i < 8; ++i) {
            #pragma unroll
            for (int m = 8; m >= 1; m >>= 1) {
                float od = __shfl_xor(dmin[i], m);
                int   ok = __shfl_xor(kmin[i], m);
                if (od < dmin[i] || (od == dmin[i] && ok < kmin[i])) {
                    dmin[i] = od; kmin[i] = ok;
                }
                dev[i] += __shfl_xor(dev[i], m);
                sw[i]  += __shfl_xor(sw[i], m);
            }
        }

        // per-row update: f32 residual chain, losses, codes
        #pragma unroll
        for (int i = 0; i < 8; ++i) {
            const int row = 8 * ty + i;
            const size_t n = (size_t)rowBase + row;
            const int bestk = kmin[i];

            const float4* q4p = (const float4*)(cbL + (size_t)bestk * DIMD);
            float4 qa = q4p[2 * tx], qb = q4p[2 * tx + 1];
            float4 ra = rS4[row * 33 + 2 * tx], rb = rS4[row * 33 + 2 * tx + 1];

            // newres = fl32(r - q) elementwise (exact replication of ref chain)
            float nr0 = ra.x - qa.x, nr1 = ra.y - qa.y;
            float nr2 = ra.z - qa.z, nr3 = ra.w - qa.w;
            float nr4 = rb.x - qb.x, nr5 = rb.y - qb.y;
            float nr6 = rb.z - qb.z, nr7 = rb.w - qb.w;

            double cpart = 0.0;
            cpart += (double)(nr0 * nr0); cpart += (double)(nr1 * nr1);
            cpart += (double)(nr2 * nr2); cpart += (double)(nr3 * nr3);
            cpart += (double)(nr4 * nr4); cpart += (double)(nr5 * nr5);
            cpart += (double)(nr6 * nr6); cpart += (double)(nr7 * nr7);
            #pragma unroll
            for (int m = 8; m >= 1; m >>= 1) cpart += __shfl_xor(cpart, m);

            rS4[row * 33 + 2 * tx]     = make_float4(nr0, nr1, nr2, nr3);
            rS4[row * 33 + 2 * tx + 1] = make_float4(nr4, nr5, nr6, nr7);

            if (tx == 0) {
                codesS[row * NLEV + l] = bestk;
                out[(size_t)NROWS * DIMD + n * NLEV + l] = (float)bestk;
                commitAcc[row] += (float)cpart;
                usageAcc[row]  += sw[i] / (1024.0f + dev[i])
                                - log1pf(dev[i] * (1.0f / 1024.0f));
            }
            if (l == NLEV - 1) {
                float4 xa = x4[n * 32 + 2 * tx];
                float4 xb = x4[n * 32 + 2 * tx + 1];
                out4[n * 32 + 2 * tx] = make_float4(
                    xa.x - nr0, xa.y - nr1, xa.z - nr2, xa.w - nr3);
                out4[n * 32 + 2 * tx + 1] = make_float4(
                    xb.x - nr4, xb.y - nr5, xb.z - nr6, xb.w - nr7);
            }
        }
    }

    __syncthreads();
    float u = 0.f, cm = 0.f;
    if (tid < RB) { u = usageAcc[tid]; cm = commitAcc[tid]; }
    #pragma unroll
    for (int m = 32; m >= 1; m >>= 1) { u += __shfl_xor(u, m); cm += __shfl_xor(cm, m); }
    if ((tid & 63) == 0) {
        atomicAdd(&lossAcc[0], (double)cm);
        atomicAdd(&lossAcc[1], (double)u);
    }
}

__global__ void rvq_prep(const float* __restrict__ cb, float* __restrict__ e2g,
                         double* __restrict__ lossAcc)
{
    int k = blockIdx.x * blockDim.x + threadIdx.x;   // 0..4095
    if (k == 0) { lossAcc[0] = 0.0; lossAcc[1] = 0.0; }
    if (k < NLEV * KCB) {
        e2g[k] = np_sumsq128(cb + (size_t)k * DIMD);  // same np pairwise tree
    }
}

__global__ void rvq_fin(const double* __restrict__ lossAcc, float* __restrict__ out)
{
    out[(size_t)NROWS * DIMD + (size_t)NROWS * NLEV] =
        (float)(lossAcc[0] * (1.25 / ((double)NROWS * (double)DIMD)));
    out[(size_t)NROWS * DIMD + (size_t)NROWS * NLEV + 1] =
        (float)(lossAcc[1] / (double)NROWS);
}

extern "C" void kernel_launch(void* const* d_in, const int* in_sizes, int n_in,
                              void* d_out, int out_size, void* d_ws, size_t ws_size,
                              hipStream_t stream)
{
    const float* x  = (const float*)d_in[0];
    const float* cb = (const float*)d_in[1];
    float* out = (float*)d_out;
    double* lossAcc = (double*)d_ws;                 // [0]=commit, [1]=usage
    float* e2g = (float*)((char*)d_ws + 16);         // 4*1024 floats

    (void)hipFuncSetAttribute((const void*)rvq_main,
                              hipFuncAttributeMaxDynamicSharedMemorySize, LDS_BYTES);

    rvq_prep<<<dim3((NLEV * KCB) / 256), dim3(256), 0, stream>>>(cb, e2g, lossAcc);
    rvq_main<<<dim3(NROWS / RB), dim3(256), LDS_BYTES, stream>>>(x, cb, out, e2g, lossAcc);
    rvq_fin<<<dim3(1), dim3(1), 0, stream>>>(lossAcc, out);
}